// Round 2
// baseline (1229.478 us; speedup 1.0000x reference)
//
#include <hip/hip_runtime.h>
#include <hip/hip_bf16.h>

#define BATCH 4
#define SEQ   2048
#define DM    1024
#define NH    16
#define DK    64
#define BH    (BATCH*NH)   // 64

typedef __attribute__((ext_vector_type(8))) short  bv8;   // 8 bf16 (4 VGPRs) MFMA frag
typedef __attribute__((ext_vector_type(4))) short  sv4;   // 4 bf16 (8B)
typedef __attribute__((ext_vector_type(4))) float  f32x4;

__device__ __forceinline__ short f2b(float f) {
    unsigned u = __builtin_bit_cast(unsigned, f);
    u += 0x7fffu + ((u >> 16) & 1u);          // RNE
    return (short)(u >> 16);
}
__device__ __forceinline__ float b2f(short s) {
    unsigned u = ((unsigned)(unsigned short)s) << 16;
    return __builtin_bit_cast(float, u);
}

// ---------------------------------------------------------------------------
// GEMM (NT): C[m][n] = sum_k A[m][k] * W[n][k].  M=8192, N=1024, K=1024.
// A_BF16: A is bf16 (ctx) else fp32 (x).  FINAL: write fp32 to FO[m*1024+n];
// else blockIdx.z selects Wq/Wk/Wv. Q,K get RoPE fused in the epilogue
// (pair partner is lane lm^1 -> __shfl_xor), Q additionally scaled by 1/8.
// V is stored transposed [BH][64][S] for the attention PV B-fragments.
// ---------------------------------------------------------------------------
template<bool A_BF16, bool FINAL>
__global__ __launch_bounds__(256) void gemm_nt(
    const float* __restrict__ Af, const short* __restrict__ Abf,
    const float* __restrict__ W0, const float* __restrict__ W1, const float* __restrict__ W2,
    short* __restrict__ Oq, short* __restrict__ Ok, short* __restrict__ Ov,
    float* __restrict__ FO)
{
    constexpr int K = 1024;
    __shared__ __align__(16) short As[128][40];
    __shared__ __align__(16) short Ws[128][40];

    const int bn = blockIdx.x, bm = blockIdx.y, bz = blockIdx.z;
    const float* __restrict__ W = (bz == 0) ? W0 : (bz == 1) ? W1 : W2;
    const int tid = threadIdx.x;
    const int wave = tid >> 6, lane = tid & 63, lm = lane & 15, lq = lane >> 4;
    const int wr = wave >> 1, wc = wave & 1;
    const int row0 = bm * 128, col0 = bn * 128;

    f32x4 acc[4][4];
    for (int i = 0; i < 4; i++)
        for (int j = 0; j < 4; j++)
            acc[i][j] = f32x4{0.f, 0.f, 0.f, 0.f};

    for (int kk = 0; kk < K; kk += 32) {
        if constexpr (A_BF16) {
            for (int p = 0; p < 2; ++p) {
                int lin = p * 2048 + tid * 8;
                int r = lin >> 5, c = lin & 31;
                *(bv8*)&As[r][c] = *(const bv8*)(Abf + (size_t)(row0 + r) * K + kk + c);
            }
        } else {
            for (int p = 0; p < 4; ++p) {
                int lin = p * 1024 + tid * 4;
                int r = lin >> 5, c = lin & 31;
                float4 v = *(const float4*)(Af + (size_t)(row0 + r) * K + kk + c);
                sv4 s; s.x = f2b(v.x); s.y = f2b(v.y); s.z = f2b(v.z); s.w = f2b(v.w);
                *(sv4*)&As[r][c] = s;
            }
        }
        for (int p = 0; p < 4; ++p) {
            int lin = p * 1024 + tid * 4;
            int r = lin >> 5, c = lin & 31;
            float4 v = *(const float4*)(W + (size_t)(col0 + r) * K + kk + c);
            sv4 s; s.x = f2b(v.x); s.y = f2b(v.y); s.z = f2b(v.z); s.w = f2b(v.w);
            *(sv4*)&Ws[r][c] = s;
        }
        __syncthreads();

        bv8 af[4], bf[4];
        for (int mt = 0; mt < 4; mt++) af[mt] = *(const bv8*)&As[wr * 64 + mt * 16 + lm][lq * 8];
        for (int nt = 0; nt < 4; nt++) bf[nt] = *(const bv8*)&Ws[wc * 64 + nt * 16 + lm][lq * 8];
        for (int mt = 0; mt < 4; mt++)
            for (int nt = 0; nt < 4; nt++)
                acc[mt][nt] = __builtin_amdgcn_mfma_f32_16x16x32_bf16(af[mt], bf[nt], acc[mt][nt], 0, 0, 0);
        __syncthreads();
    }

    // epilogue: D layout col = lane&15, row = (lane>>4)*4 + reg  [m89-verified]
    const float qscale = (bz == 0 && !FINAL) ? 0.125f : 1.0f;
    for (int mt = 0; mt < 4; mt++) {
        int mbase = row0 + wr * 64 + mt * 16 + lq * 4;
        for (int nt = 0; nt < 4; nt++) {
            int n = col0 + wc * 64 + nt * 16 + lm;
            for (int r = 0; r < 4; r++) {
                float v = acc[mt][nt][r];
                int row = mbase + r;
                if constexpr (FINAL) {
                    FO[(size_t)row * 1024 + n] = v;
                } else {
                    int b = row >> 11, s = row & 2047;
                    int h = n >> 6, d = n & 63;
                    if (bz == 2) {  // V stored transposed: [BH][64][S]
                        Ov[((size_t)((b * NH + h) * DK + d)) * SEQ + s] = f2b(v);
                    } else {
                        // fused RoPE: partner element of the (2i,2i+1) pair is lane lm^1
                        float w = __shfl_xor(v, 1, 64);
                        int i = d >> 1;
                        float ang = (float)s * exp2f((float)i * -0.41522499f); // log2(1e4)/32
                        float sn, cs;
                        sincosf(ang, &sn, &cs);
                        float out = (d & 1) ? (w * sn + v * cs) : (v * cs - w * sn);
                        out *= qscale;
                        short* dst = (bz == 0) ? Oq : Ok;
                        dst[((size_t)((b * NH + h) * SEQ + s)) * DK + d] = f2b(out);
                    }
                }
            }
        }
    }
}

// ---------------------------------------------------------------------------
// Flash-style causal attention, BARRIER-FREE. grid (S/64, BH), 256 thr = 4 waves.
// Q,K: [BH][S][64] bf16 (Q pre-scaled by 1/8); V: [BH][64][S] bf16 (transposed);
// ctx out [B][S][1024] bf16. Each wave independently owns 16 query rows; K/V
// MFMA fragments load straight from global (L1/L2-resident); only LDS use is
// the wave-private P C-layout -> A-layout transform. No __syncthreads at all.
// ---------------------------------------------------------------------------
__global__ __launch_bounds__(256) void attn_kernel(
    const short* __restrict__ Qb, const short* __restrict__ Kb,
    const short* __restrict__ Vb, short* __restrict__ Cb)
{
    __shared__ __align__(16) short Ps[4][16][72]; // per-wave P scratch (~2-way banks, free)

    const int qt = (int)gridDim.x - 1 - (int)blockIdx.x;  // heavy blocks first
    const int bh = blockIdx.y;
    const int tid = threadIdx.x, wave = tid >> 6, lane = tid & 63;
    const int lm = lane & 15, lq = lane >> 4;
    const size_t base = (size_t)bh * SEQ * DK;
    const int q0 = qt * 64;

    // Q fragments straight from global (A-layout: m=lm, k=lq*8+j)
    const short* qptr = Qb + base + (size_t)(q0 + wave * 16 + lm) * DK + lq * 8;
    bv8 aQ0 = *(const bv8*)qptr;
    bv8 aQ1 = *(const bv8*)(qptr + 32);

    f32x4 oacc[4];
    for (int nt = 0; nt < 4; nt++) oacc[nt] = f32x4{0.f, 0.f, 0.f, 0.f};
    float m_i[4], l_i[4];
    for (int r = 0; r < 4; r++) { m_i[r] = -1e30f; l_i[r] = 0.f; }

    const short* kbase = Kb + base + (size_t)lm * DK + lq * 8;
    const short* vbase = Vb + base + (size_t)lm * SEQ + lq * 8;
    const int qrow = q0 + wave * 16 + lq * 4;

    for (int kt = 0; kt <= qt; ++kt) {
        // K fragments (B-layout: n=key, k=d) and V^T fragments (n=d, k=key)
        bv8 kf0[4], kf1[4], vf0[4], vf1[4];
        for (int nt = 0; nt < 4; nt++) {
            const short* kp = kbase + (size_t)(kt * 64 + nt * 16) * DK;
            kf0[nt] = *(const bv8*)kp;
            kf1[nt] = *(const bv8*)(kp + 32);
        }
        for (int nt = 0; nt < 4; nt++) {
            const short* vp = vbase + (size_t)(nt * 16) * SEQ + kt * 64;
            vf0[nt] = *(const bv8*)vp;
            vf1[nt] = *(const bv8*)(vp + 32);
        }

        // S = Q K^T (16 rows x 64 keys per wave); Q already carries 1/sqrt(dk)
        f32x4 sc[4];
        for (int nt = 0; nt < 4; nt++) {
            sc[nt] = f32x4{0.f, 0.f, 0.f, 0.f};
            sc[nt] = __builtin_amdgcn_mfma_f32_16x16x32_bf16(aQ0, kf0[nt], sc[nt], 0, 0, 0);
            sc[nt] = __builtin_amdgcn_mfma_f32_16x16x32_bf16(aQ1, kf1[nt], sc[nt], 0, 0, 0);
        }

        // causal mask only on the diagonal tile (wave-uniform branch)
        if (kt == qt) {
            for (int nt = 0; nt < 4; nt++) {
                int key = kt * 64 + nt * 16 + lm;
                for (int r = 0; r < 4; r++)
                    sc[nt][r] = (key <= qrow + r) ? sc[nt][r] : -1e30f;
            }
        }

        // row max (16-lane butterfly within the C-layout row group)
        float rmax[4] = {-1e30f, -1e30f, -1e30f, -1e30f};
        for (int nt = 0; nt < 4; nt++)
            for (int r = 0; r < 4; r++)
                rmax[r] = fmaxf(rmax[r], sc[nt][r]);
        for (int r = 0; r < 4; r++)
            for (int off = 1; off < 16; off <<= 1)
                rmax[r] = fmaxf(rmax[r], __shfl_xor(rmax[r], off, 64));

        float alpha[4], rsum[4];
        for (int r = 0; r < 4; r++) {
            float mn = fmaxf(m_i[r], rmax[r]);
            alpha[r] = __expf(m_i[r] - mn);
            m_i[r] = mn;
            rsum[r] = 0.f;
        }
        for (int nt = 0; nt < 4; nt++)
            for (int r = 0; r < 4; r++) {
                float p = __expf(sc[nt][r] - m_i[r]);
                sc[nt][r] = p;
                rsum[r] += p;
            }
        for (int r = 0; r < 4; r++)
            for (int off = 1; off < 16; off <<= 1)
                rsum[r] += __shfl_xor(rsum[r], off, 64);
        for (int r = 0; r < 4; r++) l_i[r] = l_i[r] * alpha[r] + rsum[r];
        for (int nt = 0; nt < 4; nt++)
            for (int r = 0; r < 4; r++) oacc[nt][r] *= alpha[r];

        // P: C-layout -> LDS -> A-layout (wave-private; DS ops are in-order per wave)
        for (int nt = 0; nt < 4; nt++)
            for (int r = 0; r < 4; r++)
                Ps[wave][lq * 4 + r][nt * 16 + lm] = f2b(sc[nt][r]);
        asm volatile("s_waitcnt lgkmcnt(0)" ::: "memory");
        bv8 aP0 = *(const bv8*)&Ps[wave][lm][lq * 8];
        bv8 aP1 = *(const bv8*)&Ps[wave][lm][32 + lq * 8];
        for (int nt = 0; nt < 4; nt++) {
            oacc[nt] = __builtin_amdgcn_mfma_f32_16x16x32_bf16(aP0, vf0[nt], oacc[nt], 0, 0, 0);
            oacc[nt] = __builtin_amdgcn_mfma_f32_16x16x32_bf16(aP1, vf1[nt], oacc[nt], 0, 0, 0);
        }
    }

    // epilogue: ctx[b][s][h*64+d] bf16
    int b = bh >> 4, h = bh & 15;
    for (int r = 0; r < 4; r++) {
        float inv = 1.0f / l_i[r];
        int srow = q0 + wave * 16 + lq * 4 + r;
        size_t rowbase = ((size_t)(b * SEQ + srow)) * DM + h * DK;
        for (int nt = 0; nt < 4; nt++)
            Cb[rowbase + nt * 16 + lm] = f2b(oacc[nt][r] * inv);
    }
}

// ---------------------------------------------------------------------------
extern "C" void kernel_launch(void* const* d_in, const int* in_sizes, int n_in,
                              void* d_out, int out_size, void* d_ws, size_t ws_size,
                              hipStream_t stream)
{
    const float* x  = (const float*)d_in[0];
    const float* Wq = (const float*)d_in[1];
    const float* Wk = (const float*)d_in[2];
    const float* Wv = (const float*)d_in[3];
    const float* Wo = (const float*)d_in[4];
    float* out = (float*)d_out;

    const size_t TSZ = (size_t)BH * SEQ * DK;   // 8,388,608 elems per tensor
    short* Qb = (short*)d_ws;
    short* Kb = Qb + TSZ;
    short* Vb = Kb + TSZ;
    short* Cb = Vb + TSZ;                       // ctx [B][S][1024]

    // QKV projection (+fused RoPE on Q,K; Q pre-scaled by 1/8; V transposed)
    gemm_nt<false, false><<<dim3(8, 64, 3), 256, 0, stream>>>(
        x, nullptr, Wq, Wk, Wv, Qb, Kb, Vb, nullptr);
    // causal flash attention (barrier-free)
    attn_kernel<<<dim3(SEQ / 64, BH), 256, 0, stream>>>(Qb, Kb, Vb, Cb);
    // output projection (fp32 out)
    gemm_nt<true, true><<<dim3(8, 64, 1), 256, 0, stream>>>(
        nullptr, Cb, Wo, nullptr, nullptr, nullptr, nullptr, nullptr, out);
}